// Round 1
// baseline (109.437 us; speedup 1.0000x reference)
//
#include <hip/hip_runtime.h>

// Problem constants (B=4, N=512, D_in=512, D_out=256), fp32 in/out.
constexpr int Bq   = 4;
constexpr int Nq   = 512;
constexpr int DIN  = 512;
constexpr int DOUT = 256;

typedef _Float16 h2  __attribute__((ext_vector_type(2)));
typedef _Float16 h8  __attribute__((ext_vector_type(8)));
typedef float    f4v __attribute__((ext_vector_type(4)));
typedef float    v2f __attribute__((ext_vector_type(2)));

#if defined(__has_builtin) && __has_builtin(__builtin_amdgcn_fdot2)
__device__ __forceinline__ float fdot2f(h2 a, h2 b, float c) {
    return __builtin_amdgcn_fdot2(a, b, c, false);   // v_dot2_f32_f16
}
#else
__device__ __forceinline__ float fdot2f(h2 a, h2 b, float c) {
    return (float)a.x * (float)b.x + (float)a.y * (float)b.y + c;
}
#endif

__device__ __forceinline__ h8 cvt8(float4 lo, float4 hi) {
    h8 r;
    r[0] = (_Float16)lo.x; r[1] = (_Float16)lo.y;
    r[2] = (_Float16)lo.z; r[3] = (_Float16)lo.w;
    r[4] = (_Float16)hi.x; r[5] = (_Float16)hi.y;
    r[6] = (_Float16)hi.z; r[7] = (_Float16)hi.w;
    return r;
}

// ---------------------------------------------------------------------------
// K1: Wh = H @ W^T via MFMA 16x16x32 f16, with fp32->fp16 conversion fused
// in-register (k0 eliminated). Grid 513 x 256 thr (4 waves); block 512 only
// converts `a` (64 threads).
// Wave = one 16x16 output tile: mt = bid>>2 -> (b = mt&3, n0 = (mt>>2)*16);
// o0 = (bid&3)*64 + wave*16. K-loop: 16 mfma, A from H fp32 (lane m=col),
// B from W fp32 (lane n=col), 2x dwordx4/lane/iter each + cvt, depth-1
// prefetch. Epilogue: Wh fp32 + Wh16[n][o2] + WhT16p[b][o2][j] (pack via
// shfl_xor 1). Fragment layouts per guide: A[m=lane&15][k=quad*8+j];
// C col=lane&15, row=quad*4+reg. No LDS, no barriers.
// ---------------------------------------------------------------------------
__global__ __launch_bounds__(256) void k1_wh(const float* __restrict__ H,
                                             const float* __restrict__ W,
                                             const float* __restrict__ a,
                                             float* __restrict__ Wh,
                                             h2* __restrict__ Wh16,
                                             h2* __restrict__ WhT16p,
                                             h2* __restrict__ a16) {
    const int bid = blockIdx.x;
    const int t   = threadIdx.x;

    if (bid == 512) {                     // a conversion (tiny, one block)
        if (t < 64) {
            const int idx = 2 * t;        // h2 index (even)
            const float4 v = *(const float4*)&a[2 * idx];
            h2 h0; h0.x = (_Float16)v.x; h0.y = (_Float16)v.y;
            h2 h1; h1.x = (_Float16)v.z; h1.y = (_Float16)v.w;
            a16[idx] = h0; a16[idx + 1] = h1;
        }
        return;
    }

    const int w    = t >> 6;
    const int lane = t & 63;
    const int mt   = bid >> 2;            // 0..127
    const int b    = mt & 3;              // XCD spread
    const int n0   = (mt >> 2) << 4;      // 0..496
    const int o0   = ((bid & 3) << 6) + (w << 4);
    const int quad = lane >> 4;
    const int col  = lane & 15;

    // A: lane reads H row (n0+col) fp32, k offset quad*8 (+kb*32)
    const float4* __restrict__ aP =
        (const float4*)(H + (size_t)(b * Nq + n0 + col) * DIN) + quad * 2;
    // B: lane reads W row (o0+col) fp32, same k offsets
    const float4* __restrict__ bP =
        (const float4*)(W + (size_t)(o0 + col) * DIN) + quad * 2;

    f4v acc = {0.f, 0.f, 0.f, 0.f};
    float4 fa0 = aP[0], fa1 = aP[1];
    float4 fb0 = bP[0], fb1 = bP[1];

#pragma unroll
    for (int kb = 0; kb < 16; ++kb) {
        float4 na0 = fa0, na1 = fa1, nb0 = fb0, nb1 = fb1;
        if (kb < 15) {                    // depth-1 prefetch (8 float4 / kb)
            na0 = aP[(kb + 1) * 8];
            na1 = aP[(kb + 1) * 8 + 1];
            nb0 = bP[(kb + 1) * 8];
            nb1 = bP[(kb + 1) * 8 + 1];
        }
        const h8 af = cvt8(fa0, fa1);
        const h8 bf = cvt8(fb0, fb1);
        acc = __builtin_amdgcn_mfma_f32_16x16x32_f16(af, bf, acc, 0, 0, 0);
        fa0 = na0; fa1 = na1; fb0 = nb0; fb1 = nb1;
    }

    const int rowb = b * Nq + n0 + quad * 4;   // global row of reg 0
#pragma unroll
    for (int reg = 0; reg < 4; ++reg) {
        const float v = acc[reg];
        Wh[(size_t)(rowb + reg) * DOUT + o0 + col] = v;
        const float vp = __shfl_xor(v, 1);     // partner o
        if ((col & 1) == 0) {
            h2 hv; hv.x = (_Float16)v; hv.y = (_Float16)vp;
            const int o2 = (o0 + col) >> 1;
            Wh16[(size_t)(rowb + reg) * 128 + o2] = hv;                    // [n][o2]
            WhT16p[(size_t)b * 65536 + (size_t)o2 * 512 + (n0 + quad * 4 + reg)] = hv;
        }
    }
}

// ---------------------------------------------------------------------------
// K23: fused e+softmax (phase A, fp16 packed + dot2) and out = P @ Wh
// (phase B, pk_fma_f32). Grid 512 = (b, 4 i-rows), 1024 threads.
// Phase A also computes r_j = a.Wh_j (one extra dot2/o2) and publishes the
// combined r in LDS. Uniforms (a16, Wh16 rows) stay global s_loads (R8:
// LDS-staging them spills). Reduce loops now gated to h==0 waves only
// (h==1 waves go straight to the barriers instead of shuffling filler).
// ---------------------------------------------------------------------------
__global__ __launch_bounds__(1024, 8) void k23(const float* __restrict__ Wh,
                                               const h2* __restrict__ Wh16,
                                               const h2* __restrict__ WhT16p,
                                               const h2* __restrict__ a16,
                                               float* __restrict__ out) {
    const int t   = threadIdx.x;
    const int blk = blockIdx.x;           // 512
    const int b   = blk & 3;
    const int i0  = (blk >> 2) << 2;      // 4 i-rows

    __shared__ float smem[8192];          // 32 KB arena: sAb/sR (A), sPart (B)
    __shared__ float sP[4 * 512];         // 8 KB (normalized P, fp32)
    __shared__ float wred[2][4][8];

    // ======================= Phase A: e + softmax -> sP ====================
    {
        const int h  = __builtin_amdgcn_readfirstlane(t >> 9);  // 0/1
        const int j  = t & 511;
        const int ob = h * 64;            // o2 base (64 o-pairs = 128 o)

        const h2* __restrict__ wjp = WhT16p + (size_t)b * 65536 + (size_t)ob * 512 + j;
        const h2* __restrict__ wip = Wh16 + (size_t)(b * Nq + i0) * 128;  // uniform

        float ab[4] = {0.f, 0.f, 0.f, 0.f};
        float rja = 0.f;                  // this half's partial of r_j
        h2 cA[8], cB[8];

#define K2_L8(buf, kb)                                                      \
    _Pragma("unroll") for (int s = 0; s < 8; ++s)                           \
        buf[s] = wjp[((kb) + s) * 512];

#define K2_C8(buf, kb)                                                      \
    _Pragma("unroll") for (int s = 0; s < 8; ++s) {                         \
        const int o2 = ob + (kb) + s;                                       \
        const h2 a2 = a16[o2];                                  /* s_load */\
        rja = fdot2f(a2, buf[s], rja);                                      \
        _Pragma("unroll") for (int rr = 0; rr < 4; ++rr) {                  \
            const h2 wi = wip[rr * 128 + o2];                   /* s_load */\
            h2 w  = buf[s] + wi;                                /* pk_add */\
            h2 aw = __builtin_elementwise_max(w, -w);           /* pk_max */\
            ab[rr] = fdot2f(a2, aw, ab[rr]);                    /* dot2   */\
        }                                                                   \
    }

        K2_L8(cA, 0)  K2_L8(cB, 8)
        K2_C8(cA, 0)  K2_L8(cA, 16)
        K2_C8(cB, 8)  K2_L8(cB, 24)
        K2_C8(cA, 16) K2_L8(cA, 32)
        K2_C8(cB, 24) K2_L8(cB, 40)
        K2_C8(cA, 32) K2_L8(cA, 48)
        K2_C8(cB, 40) K2_L8(cB, 56)
        K2_C8(cA, 48)
        K2_C8(cB, 56)
#undef K2_L8
#undef K2_C8

        // combine halves: sAb[4][512] @ smem[0..2047], sRh @ [2048..2559],
        // final r @ [2560..3071]
        float* sAb = smem;
        float* sRh = smem + 2048;
        float* sRf = smem + 2560;
        if (h == 1) {
#pragma unroll
            for (int rr = 0; rr < 4; ++rr) sAb[rr * 512 + j] = ab[rr];
            sRh[j] = rja;
        }
        __syncthreads();

        float rj = 0.f;
        if (h == 0) {
#pragma unroll
            for (int rr = 0; rr < 4; ++rr) ab[rr] += sAb[rr * 512 + j];
            rj = rja + sRh[j];
            sRf[j] = rj;
        }
        __syncthreads();                  // sRf visible to all

        float e[4], pv[4];
        const int lane = t & 63;
        const int w    = t >> 6;          // h0: waves 0..7

        if (h == 0) {
#pragma unroll
            for (int rr = 0; rr < 4; ++rr)
                e[rr] = 0.6f * (sRf[i0 + rr] + rj) + 0.4f * ab[rr];
#pragma unroll
            for (int rr = 0; rr < 4; ++rr) {
                float v = e[rr];
#pragma unroll
                for (int off = 32; off > 0; off >>= 1) v = fmaxf(v, __shfl_xor(v, off));
                if (lane == 0) wred[0][rr][w] = v;
            }
        }
        __syncthreads();
        if (h == 0) {
#pragma unroll
            for (int rr = 0; rr < 4; ++rr) {
                const float4 q0 = *(const float4*)&wred[0][rr][0];
                const float4 q1 = *(const float4*)&wred[0][rr][4];
                const float m = fmaxf(fmaxf(fmaxf(q0.x, q0.y), fmaxf(q0.z, q0.w)),
                                      fmaxf(fmaxf(q1.x, q1.y), fmaxf(q1.z, q1.w)));
                pv[rr] = __expf(e[rr] - m);
            }
#pragma unroll
            for (int rr = 0; rr < 4; ++rr) {
                float v = pv[rr];
#pragma unroll
                for (int off = 32; off > 0; off >>= 1) v += __shfl_xor(v, off);
                if (lane == 0) wred[1][rr][w] = v;
            }
        }
        __syncthreads();
        if (h == 0) {
#pragma unroll
            for (int rr = 0; rr < 4; ++rr) {
                const float4 q0 = *(const float4*)&wred[1][rr][0];
                const float4 q1 = *(const float4*)&wred[1][rr][4];
                const float s = (q0.x + q0.y + q0.z + q0.w) + (q1.x + q1.y + q1.z + q1.w);
                sP[rr * 512 + j] = pv[rr] * (1.0f / s);
            }
        }
        __syncthreads();                  // sP ready; arena free for phase B
    }

    // ======================= Phase B: out = P @ Wh =========================
    {
        const int w16 = __builtin_amdgcn_readfirstlane(t >> 6);  // 0..15
        const int jh  = w16 & 7;          // j-octant (64 j)
        const int rh  = w16 >> 3;         // rows rh*2, rh*2+1
        const int oq  = t & 63;           // o-quad

        const float4* __restrict__ wh4 = (const float4*)(Wh + (size_t)b * Nq * DOUT) + oq;

        v2f accL[2] = {(v2f)0.f, (v2f)0.f};
        v2f accH[2] = {(v2f)0.f, (v2f)0.f};

        const int j0 = jh * 64;
        float4 bufA[4], bufB[4];
#pragma unroll
        for (int s = 0; s < 4; ++s) bufA[s] = wh4[(j0 + s) * 64];

        for (int it = 0; it < 8; ++it) {  // 8 j per it
            const int jA = j0 + it * 8, jB = jA + 4;
#pragma unroll
            for (int s = 0; s < 4; ++s) bufB[s] = wh4[(jB + s) * 64];
#pragma unroll
            for (int rr = 0; rr < 2; ++rr) {
                const float4 p4 = *(const float4*)&sP[(rh * 2 + rr) * 512 + jA];
#pragma unroll
                for (int x = 0; x < 4; ++x) {
                    const float pj = ((const float*)&p4)[x];
                    const v2f pj2 = pj;
                    const v2f wl = {bufA[x].x, bufA[x].y};
                    const v2f wh = {bufA[x].z, bufA[x].w};
                    accL[rr] = __builtin_elementwise_fma(pj2, wl, accL[rr]);
                    accH[rr] = __builtin_elementwise_fma(pj2, wh, accH[rr]);
                }
            }
            if (it < 7) {
#pragma unroll
                for (int s = 0; s < 4; ++s) bufA[s] = wh4[(jA + 8 + s) * 64];
            }
#pragma unroll
            for (int rr = 0; rr < 2; ++rr) {
                const float4 p4 = *(const float4*)&sP[(rh * 2 + rr) * 512 + jB];
#pragma unroll
                for (int x = 0; x < 4; ++x) {
                    const float pj = ((const float*)&p4)[x];
                    const v2f pj2 = pj;
                    const v2f wl = {bufB[x].x, bufB[x].y};
                    const v2f wh = {bufB[x].z, bufB[x].w};
                    accL[rr] = __builtin_elementwise_fma(pj2, wl, accL[rr]);
                    accH[rr] = __builtin_elementwise_fma(pj2, wh, accH[rr]);
                }
            }
        }

        float4* sPart = (float4*)smem;    // [8 jh][4 rows][64 oq] = 32 KB
#pragma unroll
        for (int rr = 0; rr < 2; ++rr) {
            const int row = rh * 2 + rr;
            float4 f;
            f.x = accL[rr].x; f.y = accL[rr].y; f.z = accH[rr].x; f.w = accH[rr].y;
            sPart[(jh * 4 + row) * 64 + oq] = f;
        }
        __syncthreads();

        if (t < 256) {
            const int row = t >> 6, oqq = t & 63;
            float4 fin = make_float4(0.f, 0.f, 0.f, 0.f);
#pragma unroll
            for (int j8 = 0; j8 < 8; ++j8) {
                const float4 v = sPart[(j8 * 4 + row) * 64 + oqq];
                fin.x += v.x; fin.y += v.y; fin.z += v.z; fin.w += v.w;
            }
            ((float4*)(out + ((size_t)(b * Nq) + i0 + row) * DOUT))[oqq] = fin;
        }
    }
}

// ---------------------------------------------------------------------------
extern "C" void kernel_launch(void* const* d_in, const int* in_sizes, int n_in,
                              void* d_out, int out_size, void* d_ws, size_t ws_size,
                              hipStream_t stream) {
    const float* H = (const float*)d_in[0];   // [4,512,512]
    const float* W = (const float*)d_in[1];   // [256,512]
    const float* a = (const float*)d_in[2];   // [256,1]
    float* out = (float*)d_out;               // [4,512,256]

    float* Wh  = (float*)d_ws;                 // 524288 f  (2 MB)
    h2* Wh16   = (h2*)(Wh + 524288);           // 262144 h2 (1 MB)   [n][o2]
    h2* WhT16p = Wh16 + 262144;                // 262144 h2 (1 MB)   [b][o2][j]
    h2* a16    = WhT16p + 262144;              // 128 h2

    hipLaunchKernelGGL(k1_wh, dim3(513), dim3(256),  0, stream, H, W, a, Wh, Wh16, WhT16p, a16);
    hipLaunchKernelGGL(k23,   dim3(512), dim3(1024), 0, stream, Wh, Wh16, WhT16p, a16, out);
}

// Round 2
// 101.941 us; speedup vs baseline: 1.0735x; 1.0735x over previous
//
#include <hip/hip_runtime.h>

// Problem constants (B=4, N=512, D_in=512, D_out=256), fp32 in/out.
constexpr int Bq   = 4;
constexpr int Nq   = 512;
constexpr int DIN  = 512;
constexpr int DOUT = 256;

typedef _Float16 h2  __attribute__((ext_vector_type(2)));
typedef _Float16 h8  __attribute__((ext_vector_type(8)));
typedef float    f4v __attribute__((ext_vector_type(4)));
typedef float    v2f __attribute__((ext_vector_type(2)));

#if defined(__has_builtin) && __has_builtin(__builtin_amdgcn_fdot2)
__device__ __forceinline__ float fdot2f(h2 a, h2 b, float c) {
    return __builtin_amdgcn_fdot2(a, b, c, false);   // v_dot2_f32_f16
}
#else
__device__ __forceinline__ float fdot2f(h2 a, h2 b, float c) {
    return (float)a.x * (float)b.x + (float)a.y * (float)b.y + c;
}
#endif

__device__ __forceinline__ h8 cvt8(float4 lo, float4 hi) {
    h8 r;
    r[0] = (_Float16)lo.x; r[1] = (_Float16)lo.y;
    r[2] = (_Float16)lo.z; r[3] = (_Float16)lo.w;
    r[4] = (_Float16)hi.x; r[5] = (_Float16)hi.y;
    r[6] = (_Float16)hi.z; r[7] = (_Float16)hi.w;
    return r;
}

// ---------------------------------------------------------------------------
// K1: Wh = H @ W^T via MFMA 16x16x32 f16, fp32->fp16 conversion fused
// in-register. Grid 513 x 256 thr (4 waves); block 512 only converts `a`.
// Wave = one 16x16 output tile. (Unchanged from last round.)
// ---------------------------------------------------------------------------
__global__ __launch_bounds__(256) void k1_wh(const float* __restrict__ H,
                                             const float* __restrict__ W,
                                             const float* __restrict__ a,
                                             float* __restrict__ Wh,
                                             h2* __restrict__ Wh16,
                                             h2* __restrict__ WhT16p,
                                             h2* __restrict__ a16) {
    const int bid = blockIdx.x;
    const int t   = threadIdx.x;

    if (bid == 512) {                     // a conversion (tiny, one block)
        if (t < 64) {
            const int idx = 2 * t;        // h2 index (even)
            const float4 v = *(const float4*)&a[2 * idx];
            h2 h0; h0.x = (_Float16)v.x; h0.y = (_Float16)v.y;
            h2 h1; h1.x = (_Float16)v.z; h1.y = (_Float16)v.w;
            a16[idx] = h0; a16[idx + 1] = h1;
        }
        return;
    }

    const int w    = t >> 6;
    const int lane = t & 63;
    const int mt   = bid >> 2;            // 0..127
    const int b    = mt & 3;              // XCD spread
    const int n0   = (mt >> 2) << 4;      // 0..496
    const int o0   = ((bid & 3) << 6) + (w << 4);
    const int quad = lane >> 4;
    const int col  = lane & 15;

    const float4* __restrict__ aP =
        (const float4*)(H + (size_t)(b * Nq + n0 + col) * DIN) + quad * 2;
    const float4* __restrict__ bP =
        (const float4*)(W + (size_t)(o0 + col) * DIN) + quad * 2;

    f4v acc = {0.f, 0.f, 0.f, 0.f};
    float4 fa0 = aP[0], fa1 = aP[1];
    float4 fb0 = bP[0], fb1 = bP[1];

#pragma unroll
    for (int kb = 0; kb < 16; ++kb) {
        float4 na0 = fa0, na1 = fa1, nb0 = fb0, nb1 = fb1;
        if (kb < 15) {                    // depth-1 prefetch (8 float4 / kb)
            na0 = aP[(kb + 1) * 8];
            na1 = aP[(kb + 1) * 8 + 1];
            nb0 = bP[(kb + 1) * 8];
            nb1 = bP[(kb + 1) * 8 + 1];
        }
        const h8 af = cvt8(fa0, fa1);
        const h8 bf = cvt8(fb0, fb1);
        acc = __builtin_amdgcn_mfma_f32_16x16x32_f16(af, bf, acc, 0, 0, 0);
        fa0 = na0; fa1 = na1; fb0 = nb0; fb1 = nb1;
    }

    const int rowb = b * Nq + n0 + quad * 4;   // global row of reg 0
#pragma unroll
    for (int reg = 0; reg < 4; ++reg) {
        const float v = acc[reg];
        Wh[(size_t)(rowb + reg) * DOUT + o0 + col] = v;
        const float vp = __shfl_xor(v, 1);     // partner o
        if ((col & 1) == 0) {
            h2 hv; hv.x = (_Float16)v; hv.y = (_Float16)vp;
            const int o2 = (o0 + col) >> 1;
            Wh16[(size_t)(rowb + reg) * 128 + o2] = hv;                    // [n][o2]
            WhT16p[(size_t)b * 65536 + (size_t)o2 * 512 + (n0 + quad * 4 + reg)] = hv;
        }
    }
}

// ---------------------------------------------------------------------------
// K23: fused e+softmax (phase A, fp16 packed + dot2) and out = P @ Wh
// (phase B, pk_fma_f32). Grid 512 = (b, 4 i-rows), 1024 threads.
// Phase B REDESIGNED this round: 16 waves each own a disjoint 32-j slice and
// compute ALL 4 rows -> every Wh element fetched exactly once (L2 traffic for
// phase B halved, 536->268 MB). Partials reduced in two stages inside the
// same 32 KB arena: waves 8..15 write slots 0..7; waves 0..7 read-modify-
// write their own slot (disjoint -> no extra barrier); 256 threads finish.
// ---------------------------------------------------------------------------
__global__ __launch_bounds__(1024, 8) void k23(const float* __restrict__ Wh,
                                               const h2* __restrict__ Wh16,
                                               const h2* __restrict__ WhT16p,
                                               const h2* __restrict__ a16,
                                               float* __restrict__ out) {
    const int t   = threadIdx.x;
    const int blk = blockIdx.x;           // 512
    const int b   = blk & 3;
    const int i0  = (blk >> 2) << 2;      // 4 i-rows

    __shared__ float smem[8192];          // 32 KB arena: sAb/sR (A), sPart (B)
    __shared__ float sP[4 * 512];         // 8 KB (normalized P, fp32)
    __shared__ float wred[2][4][8];

    // ======================= Phase A: e + softmax -> sP ====================
    {
        const int h  = __builtin_amdgcn_readfirstlane(t >> 9);  // 0/1
        const int j  = t & 511;
        const int ob = h * 64;            // o2 base (64 o-pairs = 128 o)

        const h2* __restrict__ wjp = WhT16p + (size_t)b * 65536 + (size_t)ob * 512 + j;
        const h2* __restrict__ wip = Wh16 + (size_t)(b * Nq + i0) * 128;  // uniform

        float ab[4] = {0.f, 0.f, 0.f, 0.f};
        float rja = 0.f;                  // this half's partial of r_j
        h2 cA[8], cB[8];

#define K2_L8(buf, kb)                                                      \
    _Pragma("unroll") for (int s = 0; s < 8; ++s)                           \
        buf[s] = wjp[((kb) + s) * 512];

#define K2_C8(buf, kb)                                                      \
    _Pragma("unroll") for (int s = 0; s < 8; ++s) {                         \
        const int o2 = ob + (kb) + s;                                       \
        const h2 a2 = a16[o2];                                  /* s_load */\
        rja = fdot2f(a2, buf[s], rja);                                      \
        _Pragma("unroll") for (int rr = 0; rr < 4; ++rr) {                  \
            const h2 wi = wip[rr * 128 + o2];                   /* s_load */\
            h2 w  = buf[s] + wi;                                /* pk_add */\
            h2 aw = __builtin_elementwise_max(w, -w);           /* pk_max */\
            ab[rr] = fdot2f(a2, aw, ab[rr]);                    /* dot2   */\
        }                                                                   \
    }

        K2_L8(cA, 0)  K2_L8(cB, 8)
        K2_C8(cA, 0)  K2_L8(cA, 16)
        K2_C8(cB, 8)  K2_L8(cB, 24)
        K2_C8(cA, 16) K2_L8(cA, 32)
        K2_C8(cB, 24) K2_L8(cB, 40)
        K2_C8(cA, 32) K2_L8(cA, 48)
        K2_C8(cB, 40) K2_L8(cB, 56)
        K2_C8(cA, 48)
        K2_C8(cB, 56)
#undef K2_L8
#undef K2_C8

        // combine halves: sAb[4][512] @ smem[0..2047], sRh @ [2048..2559],
        // final r @ [2560..3071]
        float* sAb = smem;
        float* sRh = smem + 2048;
        float* sRf = smem + 2560;
        if (h == 1) {
#pragma unroll
            for (int rr = 0; rr < 4; ++rr) sAb[rr * 512 + j] = ab[rr];
            sRh[j] = rja;
        }
        __syncthreads();

        float rj = 0.f;
        if (h == 0) {
#pragma unroll
            for (int rr = 0; rr < 4; ++rr) ab[rr] += sAb[rr * 512 + j];
            rj = rja + sRh[j];
            sRf[j] = rj;
        }
        __syncthreads();                  // sRf visible to all

        float e[4], pv[4];
        const int lane = t & 63;
        const int w    = t >> 6;          // h0: waves 0..7

        if (h == 0) {
#pragma unroll
            for (int rr = 0; rr < 4; ++rr)
                e[rr] = 0.6f * (sRf[i0 + rr] + rj) + 0.4f * ab[rr];
#pragma unroll
            for (int rr = 0; rr < 4; ++rr) {
                float v = e[rr];
#pragma unroll
                for (int off = 32; off > 0; off >>= 1) v = fmaxf(v, __shfl_xor(v, off));
                if (lane == 0) wred[0][rr][w] = v;
            }
        }
        __syncthreads();
        if (h == 0) {
#pragma unroll
            for (int rr = 0; rr < 4; ++rr) {
                const float4 q0 = *(const float4*)&wred[0][rr][0];
                const float4 q1 = *(const float4*)&wred[0][rr][4];
                const float m = fmaxf(fmaxf(fmaxf(q0.x, q0.y), fmaxf(q0.z, q0.w)),
                                      fmaxf(fmaxf(q1.x, q1.y), fmaxf(q1.z, q1.w)));
                pv[rr] = __expf(e[rr] - m);
            }
#pragma unroll
            for (int rr = 0; rr < 4; ++rr) {
                float v = pv[rr];
#pragma unroll
                for (int off = 32; off > 0; off >>= 1) v += __shfl_xor(v, off);
                if (lane == 0) wred[1][rr][w] = v;
            }
        }
        __syncthreads();
        if (h == 0) {
#pragma unroll
            for (int rr = 0; rr < 4; ++rr) {
                const float4 q0 = *(const float4*)&wred[1][rr][0];
                const float4 q1 = *(const float4*)&wred[1][rr][4];
                const float s = (q0.x + q0.y + q0.z + q0.w) + (q1.x + q1.y + q1.z + q1.w);
                sP[rr * 512 + j] = pv[rr] * (1.0f / s);
            }
        }
        __syncthreads();                  // sP ready; arena free for phase B
    }

    // ======================= Phase B: out = P @ Wh =========================
    {
        const int w16 = __builtin_amdgcn_readfirstlane(t >> 6);  // 0..15
        const int oq  = t & 63;           // o-quad (4 consecutive o)
        const int jb  = w16 * 32;         // this wave's disjoint j-slice

        const float4* __restrict__ wh4 = (const float4*)(Wh + (size_t)b * Nq * DOUT) + oq;

        f4v acc[4];
#pragma unroll
        for (int rr = 0; rr < 4; ++rr) acc[rr] = (f4v)0.f;

#pragma unroll 2
        for (int s = 0; s < 8; ++s) {     // 4 j per step
            const int j = jb + s * 4;
            const float4 w0 = wh4[(j + 0) * 64];
            const float4 w1 = wh4[(j + 1) * 64];
            const float4 w2 = wh4[(j + 2) * 64];
            const float4 w3 = wh4[(j + 3) * 64];
            const f4v v0 = {w0.x, w0.y, w0.z, w0.w};
            const f4v v1 = {w1.x, w1.y, w1.z, w1.w};
            const f4v v2 = {w2.x, w2.y, w2.z, w2.w};
            const f4v v3 = {w3.x, w3.y, w3.z, w3.w};
#pragma unroll
            for (int rr = 0; rr < 4; ++rr) {
                const float4 p4 = *(const float4*)&sP[rr * 512 + j];  // broadcast
                acc[rr] = __builtin_elementwise_fma((f4v)p4.x, v0, acc[rr]);
                acc[rr] = __builtin_elementwise_fma((f4v)p4.y, v1, acc[rr]);
                acc[rr] = __builtin_elementwise_fma((f4v)p4.z, v2, acc[rr]);
                acc[rr] = __builtin_elementwise_fma((f4v)p4.w, v3, acc[rr]);
            }
        }

        // Two-stage reduction of 16 partials inside the 32 KB arena.
        // sPart[k][rr][oq] float4, k = 0..7.
        float4* sPart = (float4*)smem;
        if (w16 >= 8) {                   // high waves publish slots 0..7
#pragma unroll
            for (int rr = 0; rr < 4; ++rr) {
                float4 f;
                f.x = acc[rr][0]; f.y = acc[rr][1]; f.z = acc[rr][2]; f.w = acc[rr][3];
                sPart[((w16 - 8) * 4 + rr) * 64 + oq] = f;
            }
        }
        __syncthreads();
        if (w16 < 8) {                    // low waves fold partner + publish
#pragma unroll
            for (int rr = 0; rr < 4; ++rr) {
                const int idx = (w16 * 4 + rr) * 64 + oq;
                const float4 v = sPart[idx];      // own slot only: no hazard
                float4 f;
                f.x = acc[rr][0] + v.x; f.y = acc[rr][1] + v.y;
                f.z = acc[rr][2] + v.z; f.w = acc[rr][3] + v.w;
                sPart[idx] = f;
            }
        }
        __syncthreads();

        if (t < 256) {                    // final 8-way fold + store
            const int row = t >> 6, oqq = t & 63;
            f4v fin = (f4v)0.f;
#pragma unroll
            for (int k = 0; k < 8; ++k) {
                const float4 v = sPart[(k * 4 + row) * 64 + oqq];
                fin[0] += v.x; fin[1] += v.y; fin[2] += v.z; fin[3] += v.w;
            }
            float4 f;
            f.x = fin[0]; f.y = fin[1]; f.z = fin[2]; f.w = fin[3];
            ((float4*)(out + ((size_t)(b * Nq) + i0 + row) * DOUT))[oqq] = f;
        }
    }
}

// ---------------------------------------------------------------------------
extern "C" void kernel_launch(void* const* d_in, const int* in_sizes, int n_in,
                              void* d_out, int out_size, void* d_ws, size_t ws_size,
                              hipStream_t stream) {
    const float* H = (const float*)d_in[0];   // [4,512,512]
    const float* W = (const float*)d_in[1];   // [256,512]
    const float* a = (const float*)d_in[2];   // [256,1]
    float* out = (float*)d_out;               // [4,512,256]

    float* Wh  = (float*)d_ws;                 // 524288 f  (2 MB)
    h2* Wh16   = (h2*)(Wh + 524288);           // 262144 h2 (1 MB)   [n][o2]
    h2* WhT16p = Wh16 + 262144;                // 262144 h2 (1 MB)   [b][o2][j]
    h2* a16    = WhT16p + 262144;              // 128 h2

    hipLaunchKernelGGL(k1_wh, dim3(513), dim3(256),  0, stream, H, W, a, Wh, Wh16, WhT16p, a16);
    hipLaunchKernelGGL(k23,   dim3(512), dim3(1024), 0, stream, Wh, Wh16, WhT16p, a16, out);
}